// Round 5
// baseline (344.927 us; speedup 1.0000x reference)
//
#include <hip/hip_runtime.h>
#include <hip/hip_bf16.h>

// EdgeProposer R11: occupancy via accumulator halving. R10 analysis: 2
// waves/SIMD is REGISTER-bound (pool 512/SIMD; wave = 128 VGPR + 160-elem
// acc = 256 cap exactly). Fix: 64-row x 320-col blocks (grid 2048), acc
// 80/thread (acc[5][4]); true live set ~160 < 170 = 512/3, so
// launch_bounds(256,3) is safe (R8's spill was cap 170 vs live 240).
// bfr0 cross-barrier prefetch dropped (-20 regs, was worth ~5us). LDS
// 41984B (ring 2x12288B, acts[64][328] epilogue) -> 3 blocks/CU on both
// LDS (126KB) and regs (3x168<=512). Schedule = R7/R10 single-barrier
// compiler-scheduled step + distance-1 gather prefetch + setprio.
// Tripwire: WRITE_SIZE ~34MB (spill check); Occupancy should hit ~30%.

#define DD 512
#define K3 1536
#define RB 64       // rows per block
#define LDACT 328   // 320 + 8 pad (keep %8==0: 16B-aligned rows for b128)
#define BUFS 6144   // shorts per As2 buffer (3 seg * 4 rt * 64 lane * 8)

typedef short bf16x8 __attribute__((ext_vector_type(8)));
typedef float f32x4 __attribute__((ext_vector_type(4)));

__device__ inline float b2f(short s) {
    union { float f; unsigned u; } v;
    v.u = ((unsigned)(unsigned short)s) << 16;
    return v.f;
}
__device__ inline short f2b(float f) {   // RNE
    union { float fl; unsigned u; } v;
    v.fl = f;
    unsigned x = v.u;
    unsigned r = x + 0x7fffu + ((x >> 16) & 1u);
    return (short)(r >> 16);
}
__device__ inline short babsdiff(short a, short b) {
    union { float f; unsigned u; } v;
    v.f = b2f(a) - b2f(b);
    return (short)((v.u & 0x7fffffffu) >> 16);
}

// As2 fragment-major index (K-step 32, 4 row-tiles): [seg][rt][lane][8]
__device__ __forceinline__ int sidx4(int seg, int rt, int lane) {
    return ((seg * 4 + rt) * 64 + lane) * 8;
}

// cvt(abs-diff) + 3x b128 stores of one row's 8-k chunk into a buffer
__device__ __forceinline__ void writeStage(short* buf, int rtw, int lpos,
                                           bf16x8 s8, bf16x8 t8) {
    bf16x8 a8;
#pragma unroll
    for (int j = 0; j < 8; j++) a8[j] = babsdiff(s8[j], t8[j]);
    *(bf16x8*)&buf[sidx4(0, rtw, lpos)] = s8;
    *(bf16x8*)&buf[sidx4(1, rtw, lpos)] = t8;
    *(bf16x8*)&buf[sidx4(2, rtw, lpos)] = a8;
}

// f32 fallback path: load 8 f32 of src/tgt, cvt, stage
__device__ __forceinline__ void stage_f32(const float* bs, const float* bt,
                                          short* buf, int rtw, int lpos) {
    bf16x8 s8, t8;
#pragma unroll
    for (int h = 0; h < 2; h++) {
        float4 s4 = ((const float4*)bs)[h];
        float4 t4 = ((const float4*)bt)[h];
        float ss[4] = {s4.x, s4.y, s4.z, s4.w};
        float tt[4] = {t4.x, t4.y, t4.z, t4.w};
#pragma unroll
        for (int e = 0; e < 4; e++) {
            s8[h * 4 + e] = f2b(ss[e]);
            t8[h * 4 + e] = f2b(tt[e]);
        }
    }
    writeStage(buf, rtw, lpos, s8, t8);
}

// ---- workspace layout (shorts) ----
#define WT_ELEMS (320 * 1536)
#define P2T_OFF WT_ELEMS
#define R2T_OFF (WT_ELEMS + 64 * 128)
#define PREP_TOT (WT_ELEMS + 2 * 64 * 128)
#define BEL_ELEMS (8192 * 512)
#define BEL_OFF PREP_TOT

// 8 elements per thread (bf16x8 stores; all region boundaries are %8==0)
__global__ void prep_kernel(const float* __restrict__ pw1,
                            const float* __restrict__ dw1,
                            const float* __restrict__ rw1,
                            const float* __restrict__ pw2,
                            const float* __restrict__ rw2,
                            const float* __restrict__ beliefs,
                            short* __restrict__ ws, int total8) {
    int i8 = blockIdx.x * 256 + threadIdx.x;
    if (i8 >= total8) return;
    int i = i8 * 8;
    bf16x8 o;
    if (i < WT_ELEMS) {
        int n = i / K3, k = i - n * K3;   // k..k+7 share n (K3 % 8 == 0)
        const float* src;
        int stride, off;
        if (n < 128)      { src = pw1; stride = 128; off = n; }
        else if (n < 192) { src = dw1; stride = 64;  off = n - 128; }
        else              { src = rw1; stride = 128; off = n - 192; }
#pragma unroll
        for (int j = 0; j < 8; j++) o[j] = f2b(src[(k + j) * stride + off]);
    } else if (i < R2T_OFF) {
        int jj = i - P2T_OFF;
        int n = jj >> 7, k = jj & 127;
#pragma unroll
        for (int j = 0; j < 8; j++) o[j] = f2b(pw2[(k + j) * 64 + n]);
    } else if (i < PREP_TOT) {
        int jj = i - R2T_OFF;
        int n = jj >> 7, k = jj & 127;
#pragma unroll
        for (int j = 0; j < 8; j++) o[j] = f2b(rw2[(k + j) * 64 + n]);
    } else {
        const float4* b4 = (const float4*)(beliefs + (i - BEL_OFF));
        float4 x = b4[0], y = b4[1];
        float v[8] = {x.x, x.y, x.z, x.w, y.x, y.y, y.z, y.w};
#pragma unroll
        for (int j = 0; j < 8; j++) o[j] = f2b(v[j]);
    }
    *(bf16x8*)&ws[i] = o;
}

// ---- main fused kernel: 64 pairs per block, 256 threads (4 waves) ----
template<bool BF>
__global__ __launch_bounds__(256, 3) void edge_main(
    const float* __restrict__ beliefs, const short* __restrict__ bel16,
    const int* __restrict__ src_idx, const int* __restrict__ tgt_idx,
    const float* __restrict__ pb1, const float* __restrict__ db1,
    const float* __restrict__ rb1,
    const float* __restrict__ pb2, const float* __restrict__ pw3,
    const float* __restrict__ pb3,
    const float* __restrict__ dw2, const float* __restrict__ db2,
    const float* __restrict__ rb2,
    const short* __restrict__ WT, const short* __restrict__ pw2T,
    const short* __restrict__ rw2T,
    float* __restrict__ out, int N)
{
    // union: As2 double buffer (24576B K-loop) / acts[64][328] (epilogue) / idx
    __shared__ __align__(16) char smem_u[41984];

    short* As2 = (short*)smem_u;
    short (*acts)[LDACT] = (short (*)[LDACT])smem_u;
    int* sIdx = (int*)smem_u;          // alias: consumed into regs pre-loop
    int* tIdx = sIdx + RB;

    const int t = threadIdx.x;
    const int r0 = blockIdx.x * RB;
    const int w = t >> 6, lane = t & 63, q = lane >> 4, ln = lane & 15;

    if (t < RB) sIdx[t] = src_idx[r0 + t] * DD;
    else if (t < 2 * RB) tIdx[t - RB] = tgt_idx[r0 + t - RB] * DD;
    __syncthreads();

    // staging role: thread t covers row rr, k-chunk cc (8 k each).
    const int rr = t >> 2, cc = t & 3;
    const int rtw = rr >> 4;
    const int lpos = cc * 16 + (rr & 15);
    const int srow = sIdx[rr], trow = tIdx[rr];
    __syncthreads();   // idx consumed before As2 overwrites the alias

    f32x4 acc[5][4];
#pragma unroll
    for (int ct = 0; ct < 5; ct++)
#pragma unroll
        for (int rt = 0; rt < 4; rt++) acc[ct][rt] = (f32x4)(0.f);

    // ---- prologue: stage step 0 into buf0 ----
    if constexpr (BF) {
        bf16x8 s8 = *(const bf16x8*)(bel16 + srow + cc * 8);
        bf16x8 t8 = *(const bf16x8*)(bel16 + trow + cc * 8);
        writeStage(As2, rtw, lpos, s8, t8);
    } else {
        stage_f32(beliefs + srow + cc * 8, beliefs + trow + cc * 8,
                  As2, rtw, lpos);
    }
    __syncthreads();

    // ---- main loop: 16 K-steps of 32, one barrier per step ----
    for (int step = 0; step < 16; ++step) {
        short* bufC = As2 + (step & 1) * BUFS;
        short* bufN = As2 + ((step & 1) ^ 1) * BUFS;
        const int k0 = step * 32;
        const bool pf = (step < 15);
        bf16x8 ns8, nt8;

#pragma unroll
        for (int seg = 0; seg < 3; seg++) {
            bf16x8 bfr[5];
#pragma unroll
            for (int ct = 0; ct < 5; ct++) {
                int col = w * 80 + ct * 16 + ln;
                bfr[ct] = *(const bf16x8*)(WT + (size_t)col * K3 +
                                           seg * DD + k0 + q * 8);
            }
            if (seg == 2) {
                // distance-1 gather prefetch: issued after this step's bfr
                // loads (counted vmcnt for MFMA waits), consumed at the
                // pre-barrier writeStage below.
                __builtin_amdgcn_sched_barrier(0);
                if (pf) {
                    if constexpr (BF) {
                        ns8 = *(const bf16x8*)(bel16 + srow + k0 + 32 + cc * 8);
                        nt8 = *(const bf16x8*)(bel16 + trow + k0 + 32 + cc * 8);
                    }
                }
                __builtin_amdgcn_sched_barrier(0);
            }
            __builtin_amdgcn_s_setprio(1);
#pragma unroll
            for (int rt = 0; rt < 4; rt++) {
                bf16x8 af = *(const bf16x8*)&bufC[sidx4(seg, rt, lane)];
#pragma unroll
                for (int ct = 0; ct < 5; ct++)
                    acc[ct][rt] = __builtin_amdgcn_mfma_f32_16x16x32_bf16(
                        af, bfr[ct], acc[ct][rt], 0, 0, 0);
            }
            __builtin_amdgcn_s_setprio(0);
        }
        if constexpr (BF) {
            if (pf) writeStage(bufN, rtw, lpos, ns8, nt8);
        } else {
            if (pf) stage_f32(beliefs + srow + k0 + 32 + cc * 8,
                              beliefs + trow + k0 + 32 + cc * 8,
                              bufN, rtw, lpos);
        }
        __syncthreads();
    }

    // ---- epilogue: single 64-row pass; h2 lives in acts cols 0..63 ----
    // phase B: bias + relu -> acts[64][320]. C/D: col=lane&15, row=q*4+reg.
#pragma unroll
    for (int ct = 0; ct < 5; ct++) {
        int col = w * 80 + ct * 16 + ln;
        float bias = (col < 128) ? pb1[col]
                   : (col < 192) ? db1[col - 128]
                                 : rb1[col - 192];
#pragma unroll
        for (int rt = 0; rt < 4; rt++)
#pragma unroll
            for (int i = 0; i < 4; i++) {
                int lrow = rt * 16 + q * 4 + i;
                float v = acc[ct][rt][i] + bias;
                acts[lrow][col] = f2b(fmaxf(v, 0.f));
            }
    }
    __syncthreads();

    // C1: relations = relu1_r[64x128] @ rw2 + rb2 (reads acts 192..319)
    {
        f32x4 rc[4];
#pragma unroll
        for (int rt = 0; rt < 4; rt++) rc[rt] = (f32x4)(0.f);
#pragma unroll
        for (int ks = 0; ks < 4; ks++) {
            bf16x8 bfr = *(const bf16x8*)(rw2T + (w * 16 + ln) * 128 +
                                          ks * 32 + q * 8);
#pragma unroll
            for (int rt = 0; rt < 4; rt++) {
                bf16x8 afr = *(const bf16x8*)&acts[rt * 16 + ln][192 + ks * 32 + q * 8];
                rc[rt] = __builtin_amdgcn_mfma_f32_16x16x32_bf16(afr, bfr, rc[rt], 0, 0, 0);
            }
        }
        int col = w * 16 + ln;
        float bias = rb2[col];
        float* rel = out + 2 * (size_t)N;
#pragma unroll
        for (int rt = 0; rt < 4; rt++)
#pragma unroll
            for (int i = 0; i < 4; i++) {
                int grow = r0 + rt * 16 + q * 4 + i;
                rel[(size_t)grow * 64 + col] = rc[rt][i] + bias;
            }
    }

    // C2: pc = relu1_p[64x128] @ pw2 (reads acts 0..127) -> regs
    f32x4 pc[4];
    {
#pragma unroll
        for (int rt = 0; rt < 4; rt++) pc[rt] = (f32x4)(0.f);
#pragma unroll
        for (int ks = 0; ks < 4; ks++) {
            bf16x8 bfr = *(const bf16x8*)(pw2T + (w * 16 + ln) * 128 +
                                          ks * 32 + q * 8);
#pragma unroll
            for (int rt = 0; rt < 4; rt++) {
                bf16x8 afr = *(const bf16x8*)&acts[rt * 16 + ln][0 + ks * 32 + q * 8];
                pc[rt] = __builtin_amdgcn_mfma_f32_16x16x32_bf16(afr, bfr, pc[rt], 0, 0, 0);
            }
        }
    }
    __syncthreads();   // all C2 reads of acts cols 0..127 complete

    // write h2 = relu(pc + pb2) into acts cols 0..63 (now dead)
    {
        int col = w * 16 + ln;
        float bias = pb2[col];
#pragma unroll
        for (int rt = 0; rt < 4; rt++)
#pragma unroll
            for (int i = 0; i < 4; i++) {
                int lrow = rt * 16 + q * 4 + i;
                acts[lrow][col] = f2b(fmaxf(pc[rt][i] + bias, 0.f));
            }
    }
    __syncthreads();   // h2 visible

    // C3: probs (reads acts[t][0..63]); C4: directions (acts[.][128..191])
    if (t < 64) {
        float s = pb3[0];
#pragma unroll 8
        for (int k = 0; k < 64; k++) s += b2f(acts[t][k]) * pw3[k];
        float pr = 1.f / (1.f + __expf(-s));
        out[r0 + t] = pr;
    } else if (t < 128) {
        int lrow = t - 64;
        float s = db2[0];
#pragma unroll 8
        for (int k = 0; k < 64; k++) s += b2f(acts[lrow][128 + k]) * dw2[k];
        float dir = (1.f / (1.f + __expf(-s))) * 1.57079632679489662f;
        out[(size_t)N + r0 + lrow] = dir;
    }
}

extern "C" void kernel_launch(void* const* d_in, const int* in_sizes, int n_in,
                              void* d_out, int out_size, void* d_ws, size_t ws_size,
                              hipStream_t stream) {
    const float* beliefs = (const float*)d_in[0];
    const int* src = (const int*)d_in[1];
    const int* tgt = (const int*)d_in[2];
    const float* pw1 = (const float*)d_in[3];
    const float* pb1 = (const float*)d_in[4];
    const float* pw2 = (const float*)d_in[5];
    const float* pb2 = (const float*)d_in[6];
    const float* pw3 = (const float*)d_in[7];
    const float* pb3 = (const float*)d_in[8];
    const float* dw1 = (const float*)d_in[9];
    const float* db1 = (const float*)d_in[10];
    const float* dw2 = (const float*)d_in[11];
    const float* db2 = (const float*)d_in[12];
    const float* rw1 = (const float*)d_in[13];
    const float* rb1 = (const float*)d_in[14];
    const float* rw2 = (const float*)d_in[15];
    const float* rb2 = (const float*)d_in[16];

    short* ws = (short*)d_ws;
    short* WT    = ws;
    short* pw2T  = ws + P2T_OFF;
    short* rw2T  = ws + R2T_OFF;
    short* bel16 = ws + BEL_OFF;
    const int N = in_sizes[1];

    const bool useBf = ws_size >= (size_t)(PREP_TOT + BEL_ELEMS) * sizeof(short);
    const int prepElems = useBf ? (PREP_TOT + BEL_ELEMS) : PREP_TOT;
    const int prep8 = prepElems / 8;

    prep_kernel<<<(prep8 + 255) / 256, 256, 0, stream>>>(
        pw1, dw1, rw1, pw2, rw2, beliefs, ws, prep8);

    if (useBf)
        edge_main<true><<<N / RB, 256, 0, stream>>>(
            beliefs, bel16, src, tgt, pb1, db1, rb1, pb2, pw3, pb3,
            dw2, db2, rb2, WT, pw2T, rw2T, (float*)d_out, N);
    else
        edge_main<false><<<N / RB, 256, 0, stream>>>(
            beliefs, bel16, src, tgt, pb1, db1, rb1, pb2, pw3, pb3,
            dw2, db2, rb2, WT, pw2T, rw2T, (float*)d_out, N);
}

// Round 6
// 251.366 us; speedup vs baseline: 1.3722x; 1.3722x over previous
//
#include <hip/hip_runtime.h>
#include <hip/hip_bf16.h>

// EdgeProposer R12: algebraic restructure. s@W_s and t@W_t depend only on
// the 8192 distinct beliefs -> precompute tables Bs,Bt = beliefs@W (tiny
// GEMM, prep_bst) and reduce the per-pair GEMM to |s-t|@W_a: K 1536->512
// (3x less MFMA) and only one seg staged -> K-step 128 double-buffer fits
// LDS (2x32KB <= 80KB/block) -> 4 steps instead of 16 (R11 lesson: per-step
// fixed cost dominates; amortize it). Epilogue adds Bs[src]/Bt[tgt] via
// coalesced f32 gathers (tables L3-resident). Requires ws >= 31.4MB for
// f32 tables; full R10 kernel kept as fallback (useV2 gate).
// Tripwires: WRITE ~34MB (spill), absmax ~0.0078 (sum-order), VGPR<=130.

#define DD 512
#define K3 1536
#define ROWS 128
#define LDACT 328   // 320 + 8 pad (keep %8==0: 16B-aligned rows for b128)
#define BUFS 12288  // old kernel: shorts per As2 buffer
#define BUFS2 16384 // v2: shorts per As buffer (4 kk * 8 rt * 64 lane * 8)

typedef short bf16x8 __attribute__((ext_vector_type(8)));
typedef float f32x4 __attribute__((ext_vector_type(4)));

__device__ inline float b2f(short s) {
    union { float f; unsigned u; } v;
    v.u = ((unsigned)(unsigned short)s) << 16;
    return v.f;
}
__device__ inline short f2b(float f) {   // RNE
    union { float fl; unsigned u; } v;
    v.fl = f;
    unsigned x = v.u;
    unsigned r = x + 0x7fffu + ((x >> 16) & 1u);
    return (short)(r >> 16);
}
__device__ inline short babsdiff(short a, short b) {
    union { float f; unsigned u; } v;
    v.f = b2f(a) - b2f(b);
    return (short)((v.u & 0x7fffffffu) >> 16);
}
__device__ __forceinline__ bf16x8 babs8(bf16x8 s, bf16x8 t) {
    bf16x8 a;
#pragma unroll
    for (int j = 0; j < 8; j++) a[j] = babsdiff(s[j], t[j]);
    return a;
}

// ---------------- old (R10) helpers ----------------
__device__ __forceinline__ int sidx32(int seg, int rt, int lane) {
    return ((seg * 8 + rt) * 64 + lane) * 8;
}
__device__ __forceinline__ void writeStage(short* buf, int rtw, int lnw, int kcb,
                                           bf16x8 s0, bf16x8 s1,
                                           bf16x8 t0, bf16x8 t1) {
    bf16x8 a0 = babs8(s0, t0), a1 = babs8(s1, t1);
    int l0 = kcb * 16 + lnw, l1 = l0 + 16;
    *(bf16x8*)&buf[sidx32(0, rtw, l0)] = s0;
    *(bf16x8*)&buf[sidx32(0, rtw, l1)] = s1;
    *(bf16x8*)&buf[sidx32(1, rtw, l0)] = t0;
    *(bf16x8*)&buf[sidx32(1, rtw, l1)] = t1;
    *(bf16x8*)&buf[sidx32(2, rtw, l0)] = a0;
    *(bf16x8*)&buf[sidx32(2, rtw, l1)] = a1;
}
__device__ __forceinline__ void stage_f32(const float* bs, const float* bt,
                                          short* buf, int rtw, int lnw, int kcb) {
#pragma unroll
    for (int c = 0; c < 2; c++) {
        bf16x8 sb, tb, ab;
#pragma unroll
        for (int h = 0; h < 2; h++) {
            float4 s4 = ((const float4*)bs)[c * 2 + h];
            float4 t4 = ((const float4*)bt)[c * 2 + h];
            float ss[4] = {s4.x, s4.y, s4.z, s4.w};
            float tt[4] = {t4.x, t4.y, t4.z, t4.w};
#pragma unroll
            for (int e = 0; e < 4; e++) {
                int j = h * 4 + e;
                sb[j] = f2b(ss[e]);
                tb[j] = f2b(tt[e]);
                ab[j] = f2b(fabsf(ss[e] - tt[e]));
            }
        }
        int l16 = (kcb + c) * 16 + lnw;
        *(bf16x8*)&buf[sidx32(0, rtw, l16)] = sb;
        *(bf16x8*)&buf[sidx32(1, rtw, l16)] = tb;
        *(bf16x8*)&buf[sidx32(2, rtw, l16)] = ab;
    }
}

// ---- workspace layout (shorts) ----
#define WT_ELEMS (320 * 1536)
#define P2T_OFF WT_ELEMS
#define R2T_OFF (WT_ELEMS + 64 * 128)
#define PREP_TOT (WT_ELEMS + 2 * 64 * 128)
#define BEL_ELEMS (8192 * 512)
#define BEL_OFF PREP_TOT

// 8 elements per thread (bf16x8 stores; all region boundaries are %8==0)
__global__ void prep_kernel(const float* __restrict__ pw1,
                            const float* __restrict__ dw1,
                            const float* __restrict__ rw1,
                            const float* __restrict__ pw2,
                            const float* __restrict__ rw2,
                            const float* __restrict__ beliefs,
                            short* __restrict__ ws, int total8) {
    int i8 = blockIdx.x * 256 + threadIdx.x;
    if (i8 >= total8) return;
    int i = i8 * 8;
    bf16x8 o;
    if (i < WT_ELEMS) {
        int n = i / K3, k = i - n * K3;   // k..k+7 share n (K3 % 8 == 0)
        const float* src;
        int stride, off;
        if (n < 128)      { src = pw1; stride = 128; off = n; }
        else if (n < 192) { src = dw1; stride = 64;  off = n - 128; }
        else              { src = rw1; stride = 128; off = n - 192; }
#pragma unroll
        for (int j = 0; j < 8; j++) o[j] = f2b(src[(k + j) * stride + off]);
    } else if (i < R2T_OFF) {
        int jj = i - P2T_OFF;
        int n = jj >> 7, k = jj & 127;
#pragma unroll
        for (int j = 0; j < 8; j++) o[j] = f2b(pw2[(k + j) * 64 + n]);
    } else if (i < PREP_TOT) {
        int jj = i - R2T_OFF;
        int n = jj >> 7, k = jj & 127;
#pragma unroll
        for (int j = 0; j < 8; j++) o[j] = f2b(rw2[(k + j) * 64 + n]);
    } else {
        const float4* b4 = (const float4*)(beliefs + (i - BEL_OFF));
        float4 x = b4[0], y = b4[1];
        float v[8] = {x.x, x.y, x.z, x.w, y.x, y.y, y.z, y.w};
#pragma unroll
        for (int j = 0; j < 8; j++) o[j] = f2b(v[j]);
    }
    *(bf16x8*)&ws[i] = o;
}

// ---- prep_bst: Bs = beliefs @ W[0:512], Bt = beliefs @ W[512:1024] ----
// grid 256: block b -> table (b&1), rows (b>>1)*64. f32 output, no bias.
__global__ __launch_bounds__(256) void prep_bst(
    const short* __restrict__ bel16, const short* __restrict__ WT,
    float* __restrict__ Bs, float* __restrict__ Bt) {
    const int tb = blockIdx.x & 1;
    const int r0 = (blockIdx.x >> 1) * 64;
    const int t = threadIdx.x;
    const int w = t >> 6, lane = t & 63, q = lane >> 4, ln = lane & 15;
    float* Bo = tb ? Bt : Bs;
    const int koff = tb ? 512 : 0;

    f32x4 acc[5][4];
#pragma unroll
    for (int ct = 0; ct < 5; ct++)
#pragma unroll
        for (int rt = 0; rt < 4; rt++) acc[ct][rt] = (f32x4)(0.f);

#pragma unroll
    for (int k0 = 0; k0 < 512; k0 += 128)
#pragma unroll
        for (int kk = 0; kk < 4; kk++) {
            bf16x8 bfr[5];
#pragma unroll
            for (int ct = 0; ct < 5; ct++)
                bfr[ct] = *(const bf16x8*)(WT + (size_t)(w * 80 + ct * 16 + ln) * K3 +
                                           koff + k0 + kk * 32 + q * 8);
#pragma unroll
            for (int rt = 0; rt < 4; rt++) {
                bf16x8 af = *(const bf16x8*)(bel16 +
                    (size_t)(r0 + rt * 16 + ln) * DD + k0 + kk * 32 + q * 8);
#pragma unroll
                for (int ct = 0; ct < 5; ct++)
                    acc[ct][rt] = __builtin_amdgcn_mfma_f32_16x16x32_bf16(
                        af, bfr[ct], acc[ct][rt], 0, 0, 0);
            }
        }
#pragma unroll
    for (int ct = 0; ct < 5; ct++)
#pragma unroll
        for (int rt = 0; rt < 4; rt++)
#pragma unroll
            for (int i = 0; i < 4; i++)
                Bo[(size_t)(r0 + rt * 16 + q * 4 + i) * 320 +
                   w * 80 + ct * 16 + ln] = acc[ct][rt][i];
}

// ---- v2 main kernel: |s-t| @ W_a only; K=512, 4 steps of 128 ----
__global__ __launch_bounds__(256, 2) void edge_main2(
    const short* __restrict__ bel16,
    const int* __restrict__ src_idx, const int* __restrict__ tgt_idx,
    const float* __restrict__ Bs, const float* __restrict__ Bt,
    const float* __restrict__ pb1, const float* __restrict__ db1,
    const float* __restrict__ rb1,
    const float* __restrict__ pb2, const float* __restrict__ pw3,
    const float* __restrict__ pb3,
    const float* __restrict__ dw2, const float* __restrict__ db2,
    const float* __restrict__ rb2,
    const short* __restrict__ WT, const short* __restrict__ pw2T,
    const short* __restrict__ rw2T,
    float* __restrict__ out, int N)
{
    // union: As dbuf 2x32KB (K-loop) / acts[64][328] (epilogue)
    __shared__ __align__(16) char smem_u[65536];
    __shared__ int sIdxR[ROWS], tIdxR[ROWS];   // raw idx, live whole kernel
    short* As = (short*)smem_u;
    short (*acts)[LDACT] = (short (*)[LDACT])smem_u;

    const int t = threadIdx.x;
    const int r0 = blockIdx.x * ROWS;
    const int w = t >> 6, lane = t & 63, q = lane >> 4, ln = lane & 15;

    if (t < ROWS) sIdxR[t] = src_idx[r0 + t];
    else tIdxR[t - ROWS] = tgt_idx[r0 + t - ROWS];
    __syncthreads();

    // staging role: pair (t,t^1) covers row rr; kh = 64-k half of the 128-k
    // step. Thread stages chunks gg = kh*8 + c (c=0..7), 8 bf16 each.
    const int rr = t >> 1, kh = t & 1;
    const int rtw = rr >> 4, lnw = rr & 15;
    const size_t srow = (size_t)sIdxR[rr] * DD + kh * 64;
    const size_t trow = (size_t)tIdxR[rr] * DD + kh * 64;

    f32x4 acc[5][8];
#pragma unroll
    for (int ct = 0; ct < 5; ct++)
#pragma unroll
        for (int rt = 0; rt < 8; rt++) acc[ct][rt] = (f32x4)(0.f);

    // prologue: stage step 0 (k0=0) |s-t| into buf0
#pragma unroll
    for (int c = 0; c < 8; c++) {
        bf16x8 s8 = *(const bf16x8*)(bel16 + srow + c * 8);
        bf16x8 t8 = *(const bf16x8*)(bel16 + trow + c * 8);
        bf16x8 a8 = babs8(s8, t8);
        int gg = kh * 8 + c, kd = gg >> 2, qd = gg & 3;
        *(bf16x8*)&As[((kd * 8 + rtw) * 64 + qd * 16 + lnw) * 8] = a8;
    }
    __syncthreads();

    // main loop: 4 K-steps of 128, one barrier per step
#pragma unroll
    for (int step = 0; step < 4; step++) {
        short* bufC = As + (step & 1) * BUFS2;
        short* bufN = As + ((step & 1) ^ 1) * BUFS2;
        const int k0 = step * 128;
        const bool pf = (step < 3);
        bf16x8 ps0, ps1, pt0, pt1;   // in-flight batch (2 chunks, 16 regs)

#pragma unroll
        for (int kk = 0; kk < 4; kk++) {
            bf16x8 bfr[5];
#pragma unroll
            for (int ct = 0; ct < 5; ct++)
                bfr[ct] = *(const bf16x8*)(WT + (size_t)(w * 80 + ct * 16 + ln) * K3 +
                                           1024 + k0 + kk * 32 + q * 8);
            // staging region: bfr issued first (older) -> MFMA bfr waits are
            // counted vmcnt(>=4), prefetch gathers (newer) stay in flight.
            __builtin_amdgcn_sched_barrier(0);
            if (pf) {
                if (kk > 0) {   // consume batch kk-1 -> chunks 2(kk-1),2(kk-1)+1
                    bf16x8 a0 = babs8(ps0, pt0), a1 = babs8(ps1, pt1);
                    int g0 = kh * 8 + 2 * (kk - 1);
                    int kd0 = g0 >> 2, qd0 = g0 & 3;
                    int g1 = g0 + 1, kd1 = g1 >> 2, qd1 = g1 & 3;
                    *(bf16x8*)&bufN[((kd0 * 8 + rtw) * 64 + qd0 * 16 + lnw) * 8] = a0;
                    *(bf16x8*)&bufN[((kd1 * 8 + rtw) * 64 + qd1 * 16 + lnw) * 8] = a1;
                }
                // issue batch kk: next step's chunks 2kk, 2kk+1
                ps0 = *(const bf16x8*)(bel16 + srow + k0 + 128 + (2 * kk) * 8);
                ps1 = *(const bf16x8*)(bel16 + srow + k0 + 128 + (2 * kk + 1) * 8);
                pt0 = *(const bf16x8*)(bel16 + trow + k0 + 128 + (2 * kk) * 8);
                pt1 = *(const bf16x8*)(bel16 + trow + k0 + 128 + (2 * kk + 1) * 8);
            }
            __builtin_amdgcn_sched_barrier(0);
            __builtin_amdgcn_s_setprio(1);
#pragma unroll
            for (int rt = 0; rt < 8; rt++) {
                bf16x8 af = *(const bf16x8*)&bufC[((kk * 8 + rt) * 64 + lane) * 8];
#pragma unroll
                for (int ct = 0; ct < 5; ct++)
                    acc[ct][rt] = __builtin_amdgcn_mfma_f32_16x16x32_bf16(
                        af, bfr[ct], acc[ct][rt], 0, 0, 0);
            }
            __builtin_amdgcn_s_setprio(0);
        }
        if (pf) {   // final consume: batch 3 -> chunks 6,7
            bf16x8 a0 = babs8(ps0, pt0), a1 = babs8(ps1, pt1);
            int g0 = kh * 8 + 6;
            int kd0 = g0 >> 2, qd0 = g0 & 3;
            int g1 = g0 + 1, kd1 = g1 >> 2, qd1 = g1 & 3;
            *(bf16x8*)&bufN[((kd0 * 8 + rtw) * 64 + qd0 * 16 + lnw) * 8] = a0;
            *(bf16x8*)&bufN[((kd1 * 8 + rtw) * 64 + qd1 * 16 + lnw) * 8] = a1;
        }
        __syncthreads();
    }

    // ---- epilogue: two 64-row halves; acc + Bs[src] + Bt[tgt] + bias ----
#pragma unroll
    for (int h = 0; h < 2; h++) {
        float bias5[5];
#pragma unroll
        for (int ct = 0; ct < 5; ct++) {
            int col = w * 80 + ct * 16 + ln;
            bias5[ct] = (col < 128) ? pb1[col]
                      : (col < 192) ? db1[col - 128]
                                    : rb1[col - 192];
        }
#pragma unroll
        for (int rt4 = 0; rt4 < 4; rt4++)
#pragma unroll
            for (int i = 0; i < 4; i++) {
                int lrow = rt4 * 16 + q * 4 + i;
                const float* bsp = Bs + (size_t)sIdxR[h * 64 + lrow] * 320 +
                                   w * 80 + ln;
                const float* btp = Bt + (size_t)tIdxR[h * 64 + lrow] * 320 +
                                   w * 80 + ln;
#pragma unroll
                for (int ct = 0; ct < 5; ct++) {
                    float v = acc[ct][h * 4 + rt4][i] +
                              bsp[ct * 16] + btp[ct * 16] + bias5[ct];
                    acts[lrow][w * 80 + ct * 16 + ln] = f2b(fmaxf(v, 0.f));
                }
            }
        __syncthreads();

        // C1: relations = relu1_r[64x128] @ rw2 + rb2 (reads acts 192..319)
        {
            f32x4 rc[4];
#pragma unroll
            for (int rt = 0; rt < 4; rt++) rc[rt] = (f32x4)(0.f);
#pragma unroll
            for (int ks = 0; ks < 4; ks++) {
                bf16x8 bfr = *(const bf16x8*)(rw2T + (w * 16 + ln) * 128 +
                                              ks * 32 + q * 8);
#pragma unroll
                for (int rt = 0; rt < 4; rt++) {
                    bf16x8 afr = *(const bf16x8*)&acts[rt * 16 + ln][192 + ks * 32 + q * 8];
                    rc[rt] = __builtin_amdgcn_mfma_f32_16x16x32_bf16(afr, bfr, rc[rt], 0, 0, 0);
                }
            }
            int col = w * 16 + ln;
            float bias = rb2[col];
            float* rel = out + 2 * (size_t)N;
#pragma unroll
            for (int rt = 0; rt < 4; rt++)
#pragma unroll
                for (int i = 0; i < 4; i++) {
                    int grow = r0 + h * 64 + rt * 16 + q * 4 + i;
                    rel[(size_t)grow * 64 + col] = rc[rt][i] + bias;
                }
        }

        // C2: pc = relu1_p[64x128] @ pw2 (reads acts 0..127) -> regs
        f32x4 pc[4];
        {
#pragma unroll
            for (int rt = 0; rt < 4; rt++) pc[rt] = (f32x4)(0.f);
#pragma unroll
            for (int ks = 0; ks < 4; ks++) {
                bf16x8 bfr = *(const bf16x8*)(pw2T + (w * 16 + ln) * 128 +
                                              ks * 32 + q * 8);
#pragma unroll
                for (int rt = 0; rt < 4; rt++) {
                    bf16x8 afr = *(const bf16x8*)&acts[rt * 16 + ln][0 + ks * 32 + q * 8];
                    pc[rt] = __builtin_amdgcn_mfma_f32_16x16x32_bf16(afr, bfr, pc[rt], 0, 0, 0);
                }
            }
        }
        __syncthreads();   // all C2 reads of acts cols 0..127 complete

        // write h2 = relu(pc + pb2) into acts cols 0..63 (now dead)
        {
            int col = w * 16 + ln;
            float bias = pb2[col];
#pragma unroll
            for (int rt = 0; rt < 4; rt++)
#pragma unroll
                for (int i = 0; i < 4; i++) {
                    int lrow = rt * 16 + q * 4 + i;
                    acts[lrow][col] = f2b(fmaxf(pc[rt][i] + bias, 0.f));
                }
        }
        __syncthreads();   // h2 visible

        // C3: probs (reads acts[t][0..63]); C4: directions (acts[.][128..191])
        if (t < 64) {
            float s = pb3[0];
#pragma unroll 8
            for (int k = 0; k < 64; k++) s += b2f(acts[t][k]) * pw3[k];
            float pr = 1.f / (1.f + __expf(-s));
            out[r0 + h * 64 + t] = pr;
        } else if (t < 128) {
            int lrow = t - 64;
            float s = db2[0];
#pragma unroll 8
            for (int k = 0; k < 64; k++) s += b2f(acts[lrow][128 + k]) * dw2[k];
            float dir = (1.f / (1.f + __expf(-s))) * 1.57079632679489662f;
            out[(size_t)N + r0 + h * 64 + lrow] = dir;
        }
        __syncthreads();   // protect acts before next half overwrites
    }
}

// ---------------- old (R10) main kernel: fallback ----------------
template<bool BF>
__global__ __launch_bounds__(256, 2) void edge_main(
    const float* __restrict__ beliefs, const short* __restrict__ bel16,
    const int* __restrict__ src_idx, const int* __restrict__ tgt_idx,
    const float* __restrict__ pb1, const float* __restrict__ db1,
    const float* __restrict__ rb1,
    const float* __restrict__ pb2, const float* __restrict__ pw3,
    const float* __restrict__ pb3,
    const float* __restrict__ dw2, const float* __restrict__ db2,
    const float* __restrict__ rb2,
    const short* __restrict__ WT, const short* __restrict__ pw2T,
    const short* __restrict__ rw2T,
    float* __restrict__ out, int N)
{
    __shared__ __align__(16) char smem_u[49152];
    short* As2 = (short*)smem_u;
    short (*acts)[LDACT] = (short (*)[LDACT])smem_u;
    int* sIdx = (int*)smem_u;
    int* tIdx = sIdx + ROWS;

    const int t = threadIdx.x;
    const int r0 = blockIdx.x * ROWS;
    const int w = t >> 6, lane = t & 63, q = lane >> 4, ln = lane & 15;

    if (t < ROWS) sIdx[t] = src_idx[r0 + t] * DD;
    else tIdx[t - ROWS] = tgt_idx[r0 + t - ROWS] * DD;
    __syncthreads();

    const int rrow = t >> 1, kh = t & 1;
    const int rtw = rrow >> 4, lnw = rrow & 15;
    const int kcb = kh * 2;
    const int srow = sIdx[rrow], trow = tIdx[rrow];
    __syncthreads();

    f32x4 acc[5][8];
#pragma unroll
    for (int ct = 0; ct < 5; ct++)
#pragma unroll
        for (int rt = 0; rt < 8; rt++) acc[ct][rt] = (f32x4)(0.f);

    bf16x8 bfr0[5];
#pragma unroll
    for (int ct = 0; ct < 5; ct++) {
        int col = w * 80 + ct * 16 + ln;
        bfr0[ct] = *(const bf16x8*)(WT + (size_t)col * K3 + q * 8);
    }
    if constexpr (BF) {
        const bf16x8* pS = (const bf16x8*)(bel16 + srow + kh * 16);
        const bf16x8* pT = (const bf16x8*)(bel16 + trow + kh * 16);
        writeStage(As2, rtw, lnw, kcb, pS[0], pS[1], pT[0], pT[1]);
    } else {
        stage_f32(beliefs + srow + kh * 16, beliefs + trow + kh * 16,
                  As2, rtw, lnw, kcb);
    }
    __syncthreads();

    for (int step = 0; step < 16; ++step) {
        short* bufC = As2 + (step & 1) * BUFS;
        short* bufN = As2 + ((step & 1) ^ 1) * BUFS;
        const int k0 = step * 32;
        const bool pf = (step < 15);
        bf16x8 ns0, ns1, nt0, nt1;

#pragma unroll
        for (int seg = 0; seg < 3; seg++) {
            bf16x8 bfr[5];
            if (seg == 0) {
#pragma unroll
                for (int ct = 0; ct < 5; ct++) bfr[ct] = bfr0[ct];
            } else {
#pragma unroll
                for (int ct = 0; ct < 5; ct++) {
                    int col = w * 80 + ct * 16 + ln;
                    bfr[ct] = *(const bf16x8*)(WT + (size_t)col * K3 +
                                               seg * DD + k0 + q * 8);
                }
            }
            if (seg == 2) {
                __builtin_amdgcn_sched_barrier(0);
                if (pf) {
                    if constexpr (BF) {
                        const bf16x8* pS = (const bf16x8*)(bel16 + srow + k0 + 32 + kh * 16);
                        const bf16x8* pT = (const bf16x8*)(bel16 + trow + k0 + 32 + kh * 16);
                        ns0 = pS[0]; ns1 = pS[1]; nt0 = pT[0]; nt1 = pT[1];
                    }
#pragma unroll
                    for (int ct = 0; ct < 5; ct++) {
                        int col = w * 80 + ct * 16 + ln;
                        bfr0[ct] = *(const bf16x8*)(WT + (size_t)col * K3 +
                                                    k0 + 32 + q * 8);
                    }
                }
                __builtin_amdgcn_sched_barrier(0);
            }
            __builtin_amdgcn_s_setprio(1);
#pragma unroll
            for (int rt = 0; rt < 8; rt++) {
                bf16x8 af = *(const bf16x8*)&bufC[sidx32(seg, rt, lane)];
#pragma unroll
                for (int ct = 0; ct < 5; ct++)
                    acc[ct][rt] = __builtin_amdgcn_mfma_f32_16x16x32_bf16(
                        af, bfr[ct], acc[ct][rt], 0, 0, 0);
            }
            __builtin_amdgcn_s_setprio(0);
        }
        if constexpr (BF) {
            if (pf) writeStage(bufN, rtw, lnw, kcb, ns0, ns1, nt0, nt1);
        } else {
            if (pf) stage_f32(beliefs + srow + k0 + 32 + kh * 16,
                              beliefs + trow + k0 + 32 + kh * 16,
                              bufN, rtw, lnw, kcb);
        }
        __syncthreads();
    }

#pragma unroll
    for (int h = 0; h < 2; h++) {
#pragma unroll
        for (int ct = 0; ct < 5; ct++) {
            int col = w * 80 + ct * 16 + ln;
            float bias = (col < 128) ? pb1[col]
                       : (col < 192) ? db1[col - 128]
                                     : rb1[col - 192];
#pragma unroll
            for (int rt4 = 0; rt4 < 4; rt4++)
#pragma unroll
                for (int i = 0; i < 4; i++) {
                    int lrow = rt4 * 16 + q * 4 + i;
                    float v = acc[ct][h * 4 + rt4][i] + bias;
                    acts[lrow][col] = f2b(fmaxf(v, 0.f));
                }
        }
        __syncthreads();
        {
            f32x4 rc[4];
#pragma unroll
            for (int rt = 0; rt < 4; rt++) rc[rt] = (f32x4)(0.f);
#pragma unroll
            for (int ks = 0; ks < 4; ks++) {
                bf16x8 bfr = *(const bf16x8*)(rw2T + (w * 16 + ln) * 128 +
                                              ks * 32 + q * 8);
#pragma unroll
                for (int rt = 0; rt < 4; rt++) {
                    bf16x8 afr = *(const bf16x8*)&acts[rt * 16 + ln][192 + ks * 32 + q * 8];
                    rc[rt] = __builtin_amdgcn_mfma_f32_16x16x32_bf16(afr, bfr, rc[rt], 0, 0, 0);
                }
            }
            int col = w * 16 + ln;
            float bias = rb2[col];
            float* rel = out + 2 * (size_t)N;
#pragma unroll
            for (int rt = 0; rt < 4; rt++)
#pragma unroll
                for (int i = 0; i < 4; i++) {
                    int grow = r0 + h * 64 + rt * 16 + q * 4 + i;
                    rel[(size_t)grow * 64 + col] = rc[rt][i] + bias;
                }
        }
        f32x4 pc[4];
        {
#pragma unroll
            for (int rt = 0; rt < 4; rt++) pc[rt] = (f32x4)(0.f);
#pragma unroll
            for (int ks = 0; ks < 4; ks++) {
                bf16x8 bfr = *(const bf16x8*)(pw2T + (w * 16 + ln) * 128 +
                                              ks * 32 + q * 8);
#pragma unroll
                for (int rt = 0; rt < 4; rt++) {
                    bf16x8 afr = *(const bf16x8*)&acts[rt * 16 + ln][0 + ks * 32 + q * 8];
                    pc[rt] = __builtin_amdgcn_mfma_f32_16x16x32_bf16(afr, bfr, pc[rt], 0, 0, 0);
                }
            }
        }
        __syncthreads();
        {
            int col = w * 16 + ln;
            float bias = pb2[col];
#pragma unroll
            for (int rt = 0; rt < 4; rt++)
#pragma unroll
                for (int i = 0; i < 4; i++) {
                    int lrow = rt * 16 + q * 4 + i;
                    acts[lrow][col] = f2b(fmaxf(pc[rt][i] + bias, 0.f));
                }
        }
        __syncthreads();
        if (t < 64) {
            float s = pb3[0];
#pragma unroll 8
            for (int k = 0; k < 64; k++) s += b2f(acts[t][k]) * pw3[k];
            float pr = 1.f / (1.f + __expf(-s));
            out[r0 + h * 64 + t] = pr;
        } else if (t < 128) {
            int lrow = t - 64;
            float s = db2[0];
#pragma unroll 8
            for (int k = 0; k < 64; k++) s += b2f(acts[lrow][128 + k]) * dw2[k];
            float dir = (1.f / (1.f + __expf(-s))) * 1.57079632679489662f;
            out[(size_t)N + r0 + h * 64 + lrow] = dir;
        }
        __syncthreads();
    }
}

extern "C" void kernel_launch(void* const* d_in, const int* in_sizes, int n_in,
                              void* d_out, int out_size, void* d_ws, size_t ws_size,
                              hipStream_t stream) {
    const float* beliefs = (const float*)d_in[0];
    const int* src = (const int*)d_in[1];
    const int* tgt = (const int*)d_in[2];
    const float* pw1 = (const float*)d_in[3];
    const float* pb1 = (const float*)d_in[4];
    const float* pw2 = (const float*)d_in[5];
    const float* pb2 = (const float*)d_in[6];
    const float* pw3 = (const float*)d_in[7];
    const float* pb3 = (const float*)d_in[8];
    const float* dw1 = (const float*)d_in[9];
    const float* db1 = (const float*)d_in[10];
    const float* dw2 = (const float*)d_in[11];
    const float* db2 = (const float*)d_in[12];
    const float* rw1 = (const float*)d_in[13];
    const float* rb1 = (const float*)d_in[14];
    const float* rw2 = (const float*)d_in[15];
    const float* rb2 = (const float*)d_in[16];

    short* ws = (short*)d_ws;
    short* WT    = ws;
    short* pw2T  = ws + P2T_OFF;
    short* rw2T  = ws + R2T_OFF;
    short* bel16 = ws + BEL_OFF;
    const int N = in_sizes[1];

    const size_t BF_BYTES = (size_t)(PREP_TOT + BEL_ELEMS) * sizeof(short);
    const size_t FULL_BYTES = BF_BYTES + (size_t)2 * 8192 * 320 * sizeof(float);
    const bool useV2 = ws_size >= FULL_BYTES;
    const bool useBf = ws_size >= BF_BYTES;
    const int prepElems = useBf ? (PREP_TOT + BEL_ELEMS) : PREP_TOT;
    const int prep8 = prepElems / 8;

    prep_kernel<<<(prep8 + 255) / 256, 256, 0, stream>>>(
        pw1, dw1, rw1, pw2, rw2, beliefs, ws, prep8);

    if (useV2) {
        float* Bsp = (float*)(ws + PREP_TOT + BEL_ELEMS);
        float* Btp = Bsp + (size_t)8192 * 320;
        prep_bst<<<256, 256, 0, stream>>>(bel16, WT, Bsp, Btp);
        edge_main2<<<N / ROWS, 256, 0, stream>>>(
            bel16, src, tgt, Bsp, Btp,
            pb1, db1, rb1, pb2, pw3, pb3, dw2, db2, rb2,
            WT, pw2T, rw2T, (float*)d_out, N);
    } else if (useBf) {
        edge_main<true><<<N / ROWS, 256, 0, stream>>>(
            beliefs, bel16, src, tgt, pb1, db1, rb1, pb2, pw3, pb3,
            dw2, db2, rb2, WT, pw2T, rw2T, (float*)d_out, N);
    } else {
        edge_main<false><<<N / ROWS, 256, 0, stream>>>(
            beliefs, bel16, src, tgt, pb1, db1, rb1, pb2, pw3, pb3,
            dw2, db2, rb2, WT, pw2T, rw2T, (float*)d_out, N);
    }
}